// Round 16
// baseline (470.358 us; speedup 1.0000x reference)
//
#include <hip/hip_runtime.h>
#include <stdint.h>

typedef __attribute__((ext_vector_type(8))) short bf16x8;
typedef __attribute__((ext_vector_type(4))) float f32x4;
typedef __attribute__((ext_vector_type(4))) unsigned short u16x4;
typedef __attribute__((ext_vector_type(4))) unsigned int u32x4;

#define NB 32
#define HH 128
#define WW 128
#define CI 128
#define CO 128
#define HO 126
#define WO 126
#define TH3 21             // tile h: 6 x 21 = 126 exactly (zero MFMA waste)
#define TW 16
#define PH3 23             // patch h = TH3 + 2
#define PWw 18             // patch w = TW + 2
#define NR3 (PH3 * PWw)    // 414 patch rows
#define RSTR 72            // shorts per LDS row (144 B): affine immediates only
#define RSTRB 144

__device__ __forceinline__ unsigned short f2bf(float f) {
  union { float f; unsigned u; } x; x.f = f;
  unsigned u = x.u;
  u += 0x7FFFu + ((u >> 16) & 1u);   // RNE round to bf16
  return (unsigned short)(u >> 16);
}

// cvt_pk_bf16_f32: RNE, packs 2 f32 -> 2 bf16 in one VALU op (no builtin on gfx950)
__device__ __forceinline__ unsigned cvtpk_bf16(float a, float b) {
  unsigned r;
  asm("v_cvt_pk_bf16_f32 %0, %1, %2" : "=v"(r) : "v"(a), "v"(b));
  return r;  // low16 = bf16(a), high16 = bf16(b)
}

// prep: [b,p][ci][co] f32 -> fragment-blocked bf16, slice-major [b][ch][p][kc]:
//   slice = (ch*9+p)*2+kc (4096 shorts each); within: f*512 + lane*8 + e
//   holds kin[b,p][ci = ch*64+kc*32+(lane>>4)*8+e][co = (f>>2)*64+(f&3)*16+(lane&15)]
__global__ void prep_kt(const float* __restrict__ kin, unsigned short* __restrict__ ktr) {
  __shared__ unsigned short t[CI * CO];  // 32 KB
  int bp = blockIdx.x;  // b*9+p, 0..287
  int b = bp / 9, p = bp % 9;
  const float* src = kin + (size_t)bp * (CI * CO);
  unsigned short* dstb = ktr + (size_t)b * (9 * CI * CO);
  for (int i = threadIdx.x; i < CI * CO / 4; i += blockDim.x) {
    f32x4 v = *(const f32x4*)(src + i * 4);
    u16x4 o;
    o.x = f2bf(v.x); o.y = f2bf(v.y); o.z = f2bf(v.z); o.w = f2bf(v.w);
    *(u16x4*)&t[i * 4] = o;
  }
  __syncthreads();
  for (int j = threadIdx.x; j < 2048; j += blockDim.x) {  // j = (sl*8+f)*64+lane
    int lane = j & 63, f = (j >> 6) & 7, sl = j >> 9;     // sl = ch*2+kc
    int ch = sl >> 1, kc = sl & 1;
    int co = (f >> 2) * 64 + (f & 3) * 16 + (lane & 15);
    int ci0 = ch * 64 + kc * 32 + (lane >> 4) * 8;
    bf16x8 v;
#pragma unroll
    for (int e = 0; e < 8; ++e) v[e] = t[(ci0 + e) * CO + co];
    int slice = (ch * 9 + p) * 2 + kc;
    *(bf16x8*)&dstb[(size_t)slice * 4096 + f * 512 + lane * 8] = v;
  }
}

// naive fallback (only if ws_size too small — not expected on this harness)
__global__ void conv_naive(const float* __restrict__ X, const float* __restrict__ Kf,
                           float* __restrict__ out) {
  int idx = blockIdx.x * blockDim.x + threadIdx.x;           // over B*HO*WO*CO
  if (idx >= NB * HO * WO * CO) return;
  int co = idx & 127, t = idx >> 7;
  int wp = t % WO; t /= WO;
  int hp = t % HO; int b = t / HO;
  const float* xb = X + (size_t)b * HH * WW * CI;
  const float* kb = Kf + (size_t)b * 9 * CI * CO;
  float s = 0.f;
  for (int p = 0; p < 9; ++p) {
    int kh = p / 3, kw = p % 3;
    const float* xr = xb + ((size_t)(hp + kh) * WW + (wp + kw)) * CI;
    const float* kr = kb + (size_t)p * CI * CO + co;
    for (int ci = 0; ci < CI; ++ci) s += xr[ci] * kr[(size_t)ci * CO];
  }
  out[idx] = s;
}

// R16 = R13 structure at 3 waves/SIMD: one persistent 768-thread block/CU
// (12 waves = 3 wr x 4 wc), __launch_bounds__(768,3) -> 170-reg cap. Wave
// slab m7 x n2 (acc 56 regs; tile h 21 divides 126 -> zero MFMA waste).
// R13 (2 waves/SIMD) sits at the m97-structure ceiling (~842 TF, MfmaUtil
// 39%); every latency/BW lever was null -> the residual is phase-locked
// serialization that only MORE WAVES can cover. R9's 3-wave test was the
// confounded non-persistent variant; this is the clean test.
__global__ __launch_bounds__(768, 3) void conv_main(
    const float* __restrict__ X, const unsigned short* __restrict__ Kt,
    float* __restrict__ out) {
  __shared__ unsigned short lds_a[2][NR3 * RSTR];  // 2 x 59616 B = 119232 B

  const int tid = threadIdx.x;
  const int lane = tid & 63;
  const int wid = tid >> 6;            // 12 waves, 3 (h) x 4 (co)
  const int wr = wid >> 2, wc = wid & 3;
  const int ks = lane >> 4, lr = lane & 15;

  // block -> (xcd, batch, w-column); 6 h-tiles swept
  const int bx = blockIdx.x;           // 0..255
  const int xcd = bx & 7, v = bx >> 3; // v: 0..31
  const int b = xcd * 4 + (v >> 3);    // 4 batches per XCD (L2-resident B)
  const int wt = v & 7;
  const int w0 = wt * TW;

  const float* xb = X + (size_t)b * HH * WW * CI;

  // ---- stage: granule g (0..4) = slot tid + 768g; row = (tid>>3) + 96g,
  // ci8 = tid&7 (8 ci = 32B fp32 -> one b128 bf16 write). live guard keeps
  // row < 414 (g=4: tid < 240).
  const int ci8 = tid & 7;
  const int row0 = tid >> 3;           // 0..95
  const int h00 = row0 / PWw, w00 = row0 - PWw * h00;
  const int dst0 = row0 * RSTR + ci8 * 8;   // shorts; granule g adds g*6912

  // ---- compute: af byte = aoff + ((m+kh)*18 + kw)*144 + kc*64 (imm) ----
  const int aoff = ((wr * 7) * PWw + lr) * RSTRB + ks * 16;

  // B: wave wc's 2 co-frags (32 co) = contiguous 1KB burst per slice.
  const unsigned short* ktw = Kt + (size_t)b * 9 * CI * CO + (wc * 2) * 512 + lane * 8;
  bf16x8 Hf[2][2];                     // ping-pong, distance-1
  auto loadB = [&](bf16x8 (&dst)[2], const unsigned short* p) {
    dst[0] = *(const bf16x8*)(p);
    dst[1] = *(const bf16x8*)(p + 512);
  };

  f32x4 zero = {0.f, 0.f, 0.f, 0.f};
  f32x4 acc[7][2];                     // 56 regs
#pragma unroll
  for (int m = 0; m < 7; ++m)
#pragma unroll
    for (int n = 0; n < 2; ++n) acc[m][n] = zero;

  float* const ob = out + (size_t)b * HO * WO * CO;

  // ---- prologue: stage pass-0 (tile 0, ch 0) into buf0; prefetch B(0,0) ----
  {
    int hC = h00, wC = w00;
#pragma unroll
    for (int g = 0; g < 5; ++g) {
      bool live = (g < 4) | (tid < 240);
      int gh = hC, gw = w0 + wC;
      bool ok = live && ((gh | gw) < HH);
      const float* sp = xb + ((size_t)(((gh & 127) << 7) + (gw & 127)) << 7) + ci8 * 8;
      f32x4 ga = *(const f32x4*)sp;
      f32x4 gb = *(const f32x4*)(sp + 4);
      if (live) {
        u32x4 o;
        o.x = ok ? cvtpk_bf16(ga.x, ga.y) : 0u;
        o.y = ok ? cvtpk_bf16(ga.z, ga.w) : 0u;
        o.z = ok ? cvtpk_bf16(gb.x, gb.y) : 0u;
        o.w = ok ? cvtpk_bf16(gb.z, gb.w) : 0u;
        *(u32x4*)&lds_a[0][dst0 + g * 6912] = o;
      }
      wC += 6; if (wC >= PWw) { wC -= PWw; hC += 6; } else hC += 5;
    }
  }
  loadB(Hf[0], ktw);
  __syncthreads();

  f32x4 gAa, gAb, gBa, gBb; bool okA = false, okB = false;
  int hC = h00, wC = w00;

#pragma unroll 1
  for (int kp = 0; kp < 12; ++kp) {    // 12 passes = 6 h-tiles x 2 ci-halves
    const int ch = kp & 1;
    const int h0 = (kp >> 1) * TH3;
    const char* rb = (const char*)&lds_a[kp & 1][0];
    unsigned short* wbuf = &lds_a[(kp + 1) & 1][0];
    const unsigned short* bq = ktw + (size_t)ch * 73728;   // ch*18*4096 shorts
    const bool stg = (kp < 11);
    const int chn = (kp + 1) & 1;
    const int h0n = ((kp + 1) >> 1) * TH3;
    const unsigned short* bqn = ktw + (size_t)chn * 73728;
    if (stg) { hC = h00; wC = w00; }

#pragma unroll
    for (int s = 0; s < 18; ++s) {     // all indices compile-time (unrolled)
      const int kh = s / 6, jj = s % 6;
      const int kw = jj >> 1, kc = jj & 1;
      // B prefetch, distance 1 (cross-pass at s=17 keeps parity: Hf[0])
      if (s < 17) loadB(Hf[(s + 1) & 1], bq + (size_t)(s + 1) * 4096);
      else if (stg) loadB(Hf[0], bqn);
      // stage WRITE g=s-2 first (frees the reg pair), then ISSUE g=s
      if (stg && s >= 2 && s < 7) {
        const int g = s - 2;
        bool live = (g < 4) | (tid < 240);
        if (live) {
          bool ok = (g & 1) ? okB : okA;
          f32x4 ga = (g & 1) ? gBa : gAa;
          f32x4 gb = (g & 1) ? gBb : gAb;
          u32x4 o;
          o.x = ok ? cvtpk_bf16(ga.x, ga.y) : 0u;
          o.y = ok ? cvtpk_bf16(ga.z, ga.w) : 0u;
          o.z = ok ? cvtpk_bf16(gb.x, gb.y) : 0u;
          o.w = ok ? cvtpk_bf16(gb.z, gb.w) : 0u;
          *(u32x4*)&wbuf[dst0 + g * 6912] = o;
        }
      }
      if (stg && s < 5) {
        bool live = (s < 4) | (tid < 240);
        int gh = h0n + hC, gw = w0 + wC;
        bool ok = live && ((gh | gw) < HH);
        const float* sp = xb + ((size_t)(((gh & 127) << 7) + (gw & 127)) << 7)
                          + chn * 64 + ci8 * 8;
        if (s & 1) { gBa = *(const f32x4*)sp; gBb = *(const f32x4*)(sp + 4); okB = ok; }
        else       { gAa = *(const f32x4*)sp; gAb = *(const f32x4*)(sp + 4); okA = ok; }
        wC += 6; if (wC >= PWw) { wC -= PWw; hC += 6; } else hC += 5;
      }
      // af reads + 14 MFMA
      {
        bf16x8 af[7];
#pragma unroll
        for (int m = 0; m < 7; ++m)
          af[m] = *(const bf16x8*)(rb + aoff +
                                   (((m + kh) * PWw + kw) * RSTRB + kc * 64));
        __builtin_amdgcn_s_setprio(1);
#pragma unroll
        for (int m = 0; m < 7; ++m)
#pragma unroll
          for (int n = 0; n < 2; ++n)
            acc[m][n] = __builtin_amdgcn_mfma_f32_16x16x32_bf16(af[m], Hf[s & 1][n],
                                                                acc[m][n], 0, 0, 0);
        __builtin_amdgcn_s_setprio(0);
      }
    }

    if (ch) {                          // tile done: epilogue + acc reset
#pragma unroll
      for (int m = 0; m < 7; ++m) {
        int hp = h0 + wr * 7 + m;      // always < 126 (6*21 = HO exactly)
        if (hp >= HO) continue;
#pragma unroll
        for (int r = 0; r < 4; ++r) {
          int wp = w0 + ks * 4 + r;
          if (wp >= WO) continue;
#pragma unroll
          for (int n = 0; n < 2; ++n) {
            int co = wc * 32 + n * 16 + lr;
            ob[((size_t)hp * WO + wp) * CO + co] = acc[m][n][r];
          }
        }
      }
#pragma unroll
      for (int m = 0; m < 7; ++m)
#pragma unroll
        for (int n = 0; n < 2; ++n) acc[m][n] = zero;
    }
    if (kp < 11) __syncthreads();      // stage(kp+1) visible; WAR on rb safe
  }
}

extern "C" void kernel_launch(void* const* d_in, const int* in_sizes, int n_in,
                              void* d_out, int out_size, void* d_ws, size_t ws_size,
                              hipStream_t stream) {
  const float* X = (const float*)d_in[0];
  const float* Kf = (const float*)d_in[1];
  float* out = (float*)d_out;
  size_t need = (size_t)NB * 9 * CI * CO * sizeof(unsigned short);  // 9.4 MB
  if (d_ws != nullptr && ws_size >= need) {
    unsigned short* ktr = (unsigned short*)d_ws;
    prep_kt<<<dim3(NB * 9), 256, 0, stream>>>(Kf, ktr);
    conv_main<<<dim3(256), 768, 0, stream>>>(X, ktr, out);
  } else {
    int total = NB * HO * WO * CO;
    conv_naive<<<(total + 255) / 256, 256, 0, stream>>>(X, Kf, out);
  }
}